// Round 1
// baseline (16208.167 us; speedup 1.0000x reference)
//
#include <hip/hip_runtime.h>
#include <stdint.h>

// DMLSTM on MI355X.
// Phase 0: transpose W fp32[1024][2560] -> Wt f16[2560][1024] (n-major, k contiguous)
// Phase 1: Zx = X @ Wx + b  (big f16-MFMA GEMM, parallel, stored f16 in ws)
// Phase 2: persistent recurrent kernel: 4 batch-groups x 64 CUs; W_h slice in LDS;
//          per-step group sync via agent-scope flags + double-buffered h in ws (LIC-coherent).

typedef _Float16 h8 __attribute__((ext_vector_type(8)));
typedef _Float16 h4v __attribute__((ext_vector_type(4)));
typedef float f4 __attribute__((ext_vector_type(4)));

#define SCOPE_AGENT __HIP_MEMORY_SCOPE_AGENT

__device__ __forceinline__ float sigf(float x) {
  x = fminf(fmaxf(x, -40.f), 40.f);
  return 1.f / (1.f + __expf(-x));
}
__device__ __forceinline__ float tanh_f(float x) {
  x = fminf(fmaxf(x, -20.f), 20.f);
  const float e = __expf(2.f * x);
  return (e - 1.f) / (e + 1.f);
}

// ---------------- Phase 0: W -> Wt (f16, transposed) ----------------
__global__ __launch_bounds__(256) void k_wt(const float* __restrict__ W,
                                            _Float16* __restrict__ Wt) {
  __shared__ __align__(16) _Float16 tl[64][68];
  const int bk = blockIdx.x & 15;   // 1024/64 = 16 tiles in k
  const int bn = blockIdx.x >> 4;   // 2560/64 = 40 tiles in n
  const int t = threadIdx.x;
  {
    const int r = t >> 2, c4 = t & 3;
    const float4* s4 = (const float4*)(W + (size_t)(bk * 64 + r) * 2560 + bn * 64 + c4 * 16);
#pragma unroll
    for (int i = 0; i < 4; i++) {
      float4 v = s4[i];
      tl[r][c4 * 16 + i * 4 + 0] = (_Float16)v.x;
      tl[r][c4 * 16 + i * 4 + 1] = (_Float16)v.y;
      tl[r][c4 * 16 + i * 4 + 2] = (_Float16)v.z;
      tl[r][c4 * 16 + i * 4 + 3] = (_Float16)v.w;
    }
  }
  __syncthreads();
  {
    const int nr = t >> 2, kk = (t & 3) * 16;
    h8 o0, o1;
#pragma unroll
    for (int i = 0; i < 8; i++) {
      o0[i] = tl[kk + i][nr];
      o1[i] = tl[kk + 8 + i][nr];
    }
    _Float16* dst = Wt + (size_t)(bn * 64 + nr) * 1024 + bk * 64 + kk;
    *(h8*)dst = o0;
    *(h8*)(dst + 8) = o1;
  }
}

// ---------------- Phase 1: Zx = X @ Wx + b ----------------
// X fp32 [64][2048][512]; Wt f16 [2560][1024] (we use k=0..511); Zx f16 ring [64][CS][2560]
__global__ __launch_bounds__(256) void k_zx(const float* __restrict__ X,
                                            const _Float16* __restrict__ Wt,
                                            const float* __restrict__ bias,
                                            _Float16* __restrict__ Zx,
                                            int s_base, int CS) {
  __shared__ __align__(16) _Float16 As[128][72];
  __shared__ __align__(16) _Float16 Bs[128][72];
  const int bid = blockIdx.x;
  const int nblk = bid % 20;        // 2560/128
  const int mblk = bid / 20;        // n-inner ordering -> concurrent blocks share X stripe (L2 reuse)
  const int tilesPerB = CS >> 7;
  const int b = mblk / tilesPerB;
  const int s0 = (mblk - b * tilesPerB) << 7;
  const int t = threadIdx.x;
  const int wid = t >> 6, lane = t & 63;
  const int wr = wid >> 1, wc = wid & 1;
  const int lr = (lane >> 4) * 4, lc = lane & 15;
  const int koff = (lane >> 4) * 8;

  const f4 zero4 = {0.f, 0.f, 0.f, 0.f};
  f4 acc[4][4];
#pragma unroll
  for (int i = 0; i < 4; i++)
#pragma unroll
    for (int j = 0; j < 4; j++) acc[i][j] = zero4;

  const float* Xb = X + ((size_t)b * 2048 + (size_t)(s_base + s0)) * 512;
  const _Float16* Bb = Wt + (size_t)nblk * 128 * 1024;
  const int rA = t >> 1, hf = t & 1;

  for (int k0 = 0; k0 < 512; k0 += 64) {
    // stage A tile [128][64] fp32 -> f16
    const float4* s4 = (const float4*)(Xb + (size_t)rA * 512 + k0 + hf * 32);
#pragma unroll
    for (int i = 0; i < 8; i++) {
      float4 v = s4[i];
      h4v o = {(_Float16)v.x, (_Float16)v.y, (_Float16)v.z, (_Float16)v.w};
      *(h4v*)&As[rA][hf * 32 + i * 4] = o;
    }
    // stage B tile: Wt rows = n, 64 k each (already f16)
    const h8* bs = (const h8*)(Bb + (size_t)rA * 1024 + k0 + hf * 32);
#pragma unroll
    for (int i = 0; i < 4; i++) *(h8*)&Bs[rA][hf * 32 + i * 8] = bs[i];
    __syncthreads();
#pragma unroll
    for (int kk = 0; kk < 2; kk++) {
      h8 af[4], bf[4];
      const int kr = kk * 32 + koff;
#pragma unroll
      for (int i = 0; i < 4; i++) af[i] = *(const h8*)&As[wr * 64 + i * 16 + lc][kr];
#pragma unroll
      for (int j = 0; j < 4; j++) bf[j] = *(const h8*)&Bs[wc * 64 + j * 16 + lc][kr];
#pragma unroll
      for (int i = 0; i < 4; i++)
#pragma unroll
        for (int j = 0; j < 4; j++)
          acc[i][j] = __builtin_amdgcn_mfma_f32_16x16x32_f16(af[i], bf[j], acc[i][j], 0, 0, 0);
    }
    __syncthreads();
  }
#pragma unroll
  for (int j = 0; j < 4; j++) {
    const int col = nblk * 128 + wc * 64 + j * 16 + lc;
    const float bc = bias[col];
#pragma unroll
    for (int i = 0; i < 4; i++) {
#pragma unroll
      for (int r = 0; r < 4; r++) {
        const int srow = s0 + wr * 64 + i * 16 + lr + r;
        Zx[((size_t)b * CS + srow) * 2560 + col] = (_Float16)(acc[i][j][r] + bc);
      }
    }
  }
}

// ---------------- Phase 2: persistent recurrence ----------------
// grid = 256 blocks x 256 thr. group grp = bid>>6 owns batches [grp*16, grp*16+16).
// CU ci = bid&63 owns H-cols [ci*8, ci*8+8) i.e. W cols {g*512 + ci*8 + j : g<5, j<8}.
__global__ __launch_bounds__(256) void k_rec(
    const _Float16* __restrict__ Zx, const _Float16* __restrict__ Wt,
    float* __restrict__ Y, uint32_t* __restrict__ hbuf,
    _Float16* __restrict__ hstate, float* __restrict__ cstate,
    uint32_t* __restrict__ flags, int s_base, int CS) {
  __shared__ __align__(16) _Float16 WsT[40][520];  // [local col][k] (k of h-part)
  __shared__ __align__(16) _Float16 hs[16][520];   // staged h(t) f16
  __shared__ __align__(16) float zsh[16][40];      // z slice fp32
  __shared__ __align__(16) _Float16 zxs[16][40];   // Zx slice for step t
  __shared__ __align__(16) float cbuf[128];        // c state [m][j]
  __shared__ __align__(16) uint16_t hn[128];       // new h f16 bits [m][j]

  const int bid = blockIdx.x;
  const int grp = bid >> 6, ci = bid & 63;
  const int tid = threadIdx.x;
  const int wid = tid >> 6, lane = tid & 63;
  const int hbase = ci * 8;

  // load W_h slice once: WsT[g*8+j][k] = Wt[g*512+hbase+j][512+k]
#pragma unroll
  for (int i = 0; i < 10; i++) {
    const int idx = i * 256 + tid;
    const int lcw = idx >> 6;   // 0..39
    const int ch = idx & 63;    // 8-f16 chunk
    const int g = lcw >> 3, j = lcw & 7;
    const h8* src = (const h8*)(Wt + (size_t)(g * 512 + hbase + j) * 1024 + 512 + ch * 8);
    *(h8*)&WsT[lcw][ch * 8] = *src;
  }
  if (tid < 128) {
    cbuf[tid] = cstate[(grp * 64 + ci) * 128 + tid];
    const int m = tid >> 3, j = tid & 7;
    _Float16 hv = hstate[(size_t)(grp * 16 + m) * 512 + hbase + j];
    hn[tid] = *(const uint16_t*)&hv;
  }
  __syncthreads();
  // publish h(0) into buffer 0
  if (wid == 0) {
    const int m = lane >> 2, q = lane & 3;
    const uint32_t v = ((const uint32_t*)hn)[lane];
    __hip_atomic_store(&hbuf[(size_t)((0 * 4 + grp) * 16 + m) * 256 + ci * 4 + q], v,
                       __ATOMIC_RELAXED, SCOPE_AGENT);
    asm volatile("s_waitcnt vmcnt(0)" ::: "memory");
    if (lane == 0)
      __hip_atomic_store(&flags[grp * 64 + ci], 1u, __ATOMIC_RELAXED, SCOPE_AGENT);
  }

  uint32_t* hs32 = (uint32_t*)&hs[0][0];

  for (int t = 0; t < CS; t++) {
    // wave 3: prefetch this step's Zx slice while wave 0 polls
    if (wid == 3) {
      for (int c = lane; c < 80; c += 64) {
        const int m = c / 5, g = c % 5;
        const h8* src =
            (const h8*)(Zx + ((size_t)(grp * 16 + m) * CS + t) * 2560 + g * 512 + hbase);
        *(h8*)&zxs[m][g * 8] = *src;
      }
    }
    if (wid == 0) {
      const uint32_t target = (uint32_t)(t + 1);
      while (true) {
        const uint32_t v =
            __hip_atomic_load(&flags[grp * 64 + lane], __ATOMIC_RELAXED, SCOPE_AGENT);
        if (__all((int)(v >= target))) break;
      }
    }
    __syncthreads();
    // stage full h(t) [16][512] f16 from LIC
    {
      const uint32_t* src = hbuf + (size_t)(((t & 1) * 4 + grp) * 16) * 256;
#pragma unroll
      for (int i = 0; i < 16; i++) {
        const uint32_t v =
            __hip_atomic_load(&src[i * 256 + tid], __ATOMIC_RELAXED, SCOPE_AGENT);
        hs32[i * 260 + tid] = v;  // row stride 520 f16 = 260 u32
      }
    }
    __syncthreads();
    // z = h @ Wh (+Zx): waves 0..2 each own one 16-col MFMA tile (cols 40..47 garbage)
    if (wid < 3) {
      f4 acc = {0.f, 0.f, 0.f, 0.f};
      const int nloc = wid * 16 + (lane & 15);
      const int wrow = nloc < 40 ? nloc : 39;
      const int koff = (lane >> 4) * 8;
#pragma unroll
      for (int ks = 0; ks < 16; ks++) {
        const h8 a = *(const h8*)&hs[lane & 15][ks * 32 + koff];
        const h8 bb = *(const h8*)&WsT[wrow][ks * 32 + koff];
        acc = __builtin_amdgcn_mfma_f32_16x16x32_f16(a, bb, acc, 0, 0, 0);
      }
      if (nloc < 40) {
        const int rb = (lane >> 4) * 4;
#pragma unroll
        for (int r = 0; r < 4; r++)
          zsh[rb + r][nloc] = acc[r] + (float)zxs[rb + r][nloc];
      }
    }
    __syncthreads();
    // gates + state update (column-local)
    if (tid < 128) {
      const int m = tid >> 3, j = tid & 7;
      const float zi = zsh[m][j], zf = zsh[m][8 + j], zo = zsh[m][16 + j];
      const float zc = zsh[m][24 + j], zd = zsh[m][32 + j];
      const float ig = sigf(zi), fg = sigf(zf), og = sigf(zo);
      const float c0 = cbuf[tid];
      const float cp = fg * c0 + ig * tanh_f(zc);
      const float dg = tanh_f(zd);
      const float cn = cp + dg * (cp - c0);
      const float hv = og * tanh_f(cn);
      cbuf[tid] = cn;
      Y[((size_t)(grp * 16 + m) * 2048 + (size_t)(s_base + t)) * 512 + hbase + j] = hv;
      const _Float16 hfv = (_Float16)hv;
      hn[tid] = *(const uint16_t*)&hfv;
      if (t == CS - 1) {
        cstate[(grp * 64 + ci) * 128 + tid] = cn;
        hstate[(size_t)(grp * 16 + m) * 512 + hbase + j] = hfv;
      }
    }
    __syncthreads();
    // publish h(t+1) slice into the other buffer; release via vmcnt drain + flag
    if (wid == 0) {
      const int m = lane >> 2, q = lane & 3;
      const uint32_t v = ((const uint32_t*)hn)[lane];
      __hip_atomic_store(
          &hbuf[(size_t)((((t + 1) & 1) * 4 + grp) * 16 + m) * 256 + ci * 4 + q], v,
          __ATOMIC_RELAXED, SCOPE_AGENT);
      asm volatile("s_waitcnt vmcnt(0)" ::: "memory");
      if (lane == 0)
        __hip_atomic_store(&flags[grp * 64 + ci], (uint32_t)(t + 2), __ATOMIC_RELAXED,
                           SCOPE_AGENT);
    }
  }
}

extern "C" void kernel_launch(void* const* d_in, const int* in_sizes, int n_in,
                              void* d_out, int out_size, void* d_ws, size_t ws_size,
                              hipStream_t stream) {
  const float* X = (const float*)d_in[0];
  const float* W = (const float*)d_in[1];
  const float* bias = (const float*)d_in[2];
  float* Y = (float*)d_out;
  char* ws = (char*)d_ws;

  const size_t szWt = (size_t)2560 * 1024 * 2;  // 5.24 MB
  // choose largest S-chunk whose Zx ring fits in ws
  int CS = 128;
  for (int c = 2048; c >= 128; c >>= 1) {
    const size_t need = szWt + (size_t)64 * c * 2560 * 2 + 400 * 1024;
    if (need <= ws_size) { CS = c; break; }
  }
  const size_t offZx = szWt;
  const size_t szZx = (size_t)64 * CS * 2560 * 2;
  const size_t offHbuf = offZx + szZx;
  const size_t szHbuf = (size_t)2 * 4 * 16 * 256 * 4;  // 131072
  const size_t offHst = offHbuf + szHbuf;
  const size_t szHst = (size_t)4 * 16 * 512 * 2;       // 65536
  const size_t offCst = offHst + szHst;
  const size_t szCst = (size_t)4 * 64 * 128 * 4;       // 131072
  const size_t offFlg = offCst + szCst;
  const size_t szFlg = 256 * 4;

  _Float16* Wt = (_Float16*)(ws + 0);
  _Float16* Zx = (_Float16*)(ws + offZx);
  uint32_t* hbuf = (uint32_t*)(ws + offHbuf);
  _Float16* hstate = (_Float16*)(ws + offHst);
  float* cstate = (float*)(ws + offCst);
  uint32_t* flags = (uint32_t*)(ws + offFlg);

  k_wt<<<640, 256, 0, stream>>>(W, Wt);
  (void)hipMemsetAsync(ws + offHst, 0, szHst + szCst, stream);  // h(0)=c(0)=0

  const int nch = 2048 / CS;
  for (int ch = 0; ch < nch; ch++) {
    const int sb = ch * CS;
    k_zx<<<CS * 10, 256, 0, stream>>>(X, Wt, bias, Zx, sb, CS);
    (void)hipMemsetAsync(ws + offFlg, 0, szFlg, stream);
    k_rec<<<256, 256, 0, stream>>>(Zx, Wt, Y, hbuf, hstate, cstate, flags, sb, CS);
  }
  (void)in_sizes; (void)n_in; (void)out_size;
}